// Round 1
// baseline (1447.582 us; speedup 1.0000x reference)
//
#include <hip/hip_runtime.h>
#include <hip/hip_bf16.h>
#include <math.h>

// Problem constants
static constexpr int B_   = 32;
static constexpr int NV_  = 1024;
static constexpr int NC_  = 1024;
static constexpr int COL_ = 1038;   // VAR_NF + NC
static constexpr int NF_  = 14;
static constexpr int E_   = 128;
static constexpr int ROWS_ = B_ * NV_;   // 32768 (= B_*NC_ too)

// ---------------------------------------------------------------------------
// Cubic B-spline bases (grid: g(j) = (j-3)*0.4 - 1, j=0..11), 8 outputs.
// Mirrors reference Cox-de Boor recursion with uniform-grid constant denoms.
// ---------------------------------------------------------------------------
__device__ __forceinline__ void bspline8(float x, float* __restrict__ bs) {
  const float h = 0.4f;
  float b0[11];
#pragma unroll
  for (int j = 0; j < 11; ++j) {
    float gj  = (float)(j - 3) * h - 1.0f;
    float gj1 = (float)(j - 2) * h - 1.0f;
    b0[j] = (x >= gj && x < gj1) ? 1.0f : 0.0f;
  }
  float b1[10];
#pragma unroll
  for (int j = 0; j < 10; ++j) {
    float gj  = (float)(j - 3) * h - 1.0f;
    float gj2 = (float)(j - 1) * h - 1.0f;
    b1[j] = ((x - gj) * b0[j] + (gj2 - x) * b0[j + 1]) * (1.0f / (1.0f * h));
  }
  float b2[9];
#pragma unroll
  for (int j = 0; j < 9; ++j) {
    float gj  = (float)(j - 3) * h - 1.0f;
    float gj3 = (float)(j)     * h - 1.0f;
    b2[j] = ((x - gj) * b1[j] + (gj3 - x) * b1[j + 1]) * (1.0f / (2.0f * h));
  }
#pragma unroll
  for (int j = 0; j < 8; ++j) {
    float gj  = (float)(j - 3) * h - 1.0f;
    float gj4 = (float)(j + 1) * h - 1.0f;
    bs[j] = ((x - gj) * b2[j] + (gj4 - x) * b2[j + 1]) * (1.0f / (3.0f * h));
  }
}

// ---------------------------------------------------------------------------
// Pack KAN weights: W9p[(i*9+q)*O + o]; q=0 -> base_w[o,i]; q=1..8 ->
// spline_w[o,i,q-1] * scaler[o,i].   (O = 128 or 1)
// ---------------------------------------------------------------------------
__global__ void k_pack9(const float* __restrict__ base,
                        const float* __restrict__ spline,
                        const float* __restrict__ scaler,
                        float* __restrict__ W9p, int O) {
  int idx = blockIdx.x * 256 + threadIdx.x;
  int total = 128 * 9 * O;
  if (idx >= total) return;
  int o = idx % O;
  int rest = idx / O;
  int q = rest % 9;
  int i = rest / 9;
  float v;
  if (q == 0) v = base[o * 128 + i];
  else        v = spline[(o * 128 + i) * 8 + (q - 1)] * scaler[o * 128 + i];
  W9p[idx] = v;
}

// ---------------------------------------------------------------------------
// Embedding: X[row,e] = sum_f obs[row*COL_+f] * W_emb[e*14+f]; 2 rows/block.
// ---------------------------------------------------------------------------
__global__ __launch_bounds__(256) void k_embed(const float* __restrict__ obs,
                                               const float* __restrict__ W_emb,
                                               float* __restrict__ X) {
  int t = threadIdx.x;
  int e = t & 127;
  size_t row = (size_t)blockIdx.x * 2 + (t >> 7);
  float w[NF_];
#pragma unroll
  for (int f = 0; f < NF_; ++f) w[f] = W_emb[e * NF_ + f];
  const float* orow = obs + row * COL_;
  float acc = 0.f;
#pragma unroll
  for (int f = 0; f < NF_; ++f) acc = fmaf(orow[f], w[f], acc);
  X[row * E_ + e] = acc;
}

// ---------------------------------------------------------------------------
// einsum 'bvc,bve->bce' : out[b,c,e] = sum_v A[b,v,c] * X[b,v,e]
// block: 128 c x 128 e, K-chunk 16, 256 threads, 8x8 microtile.
// ---------------------------------------------------------------------------
__global__ __launch_bounds__(256) void k_einsum_at(const float* __restrict__ obs,
                                                   const float* __restrict__ Xin,
                                                   float* __restrict__ out) {
  int blk = blockIdx.x;
  int b  = blk >> 3;
  int ct = blk & 7;
  const float* A  = obs + (size_t)b * NV_ * COL_ + NF_;  // A[v*COL_ + c]
  const float* Xb = Xin + (size_t)b * NV_ * E_;
  float* outb = out + (size_t)b * NC_ * E_ + (size_t)ct * 128 * E_;
  int c0 = ct * 128;

  __shared__ float As[16][128];
  __shared__ float Xs[16][128];
  int t = threadIdx.x;
  int tx = t & 15, ty = t >> 4;
  float acc[8][8] = {};

  for (int kk = 0; kk < NV_; kk += 16) {
#pragma unroll
    for (int i = 0; i < 8; ++i) {
      int l = t + i * 256;
      int r = l >> 7, c = l & 127;
      As[r][c] = A[(size_t)(kk + r) * COL_ + c0 + c];
      Xs[r][c] = Xb[(size_t)(kk + r) * E_ + c];
    }
    __syncthreads();
#pragma unroll
    for (int k = 0; k < 16; ++k) {
      float av[8], xv[8];
#pragma unroll
      for (int i = 0; i < 8; ++i) av[i] = As[k][tx + 16 * i];
#pragma unroll
      for (int j = 0; j < 8; ++j) xv[j] = Xs[k][ty + 16 * j];
#pragma unroll
      for (int i = 0; i < 8; ++i)
#pragma unroll
        for (int j = 0; j < 8; ++j) acc[i][j] = fmaf(av[i], xv[j], acc[i][j]);
    }
    __syncthreads();
  }
#pragma unroll
  for (int i = 0; i < 8; ++i)
#pragma unroll
    for (int j = 0; j < 8; ++j)
      outb[(size_t)(tx + 16 * i) * E_ + ty + 16 * j] = acc[i][j];
}

// ---------------------------------------------------------------------------
// einsum 'bvc,bce->bve' : out[b,v,e] = sum_c A[b,v,c] * Y[b,c,e]
// ---------------------------------------------------------------------------
__global__ __launch_bounds__(256) void k_einsum_a(const float* __restrict__ obs,
                                                  const float* __restrict__ Yin,
                                                  float* __restrict__ out) {
  int blk = blockIdx.x;
  int b  = blk >> 3;
  int vt = blk & 7;
  const float* A  = obs + (size_t)b * NV_ * COL_ + NF_;
  const float* Yb = Yin + (size_t)b * NC_ * E_;
  float* outb = out + (size_t)b * NV_ * E_ + (size_t)vt * 128 * E_;
  int v0 = vt * 128;

  __shared__ float As[16][129];  // As[k][v], padded
  __shared__ float Ys[16][128];
  int t = threadIdx.x;
  int tx = t & 15, ty = t >> 4;
  int vrow = t >> 1, part = t & 1;
  float acc[8][8] = {};

  for (int kk = 0; kk < NC_; kk += 16) {
    const float* src = &A[(size_t)(v0 + vrow) * COL_ + kk + part * 8];
#pragma unroll
    for (int u = 0; u < 8; ++u) As[part * 8 + u][vrow] = src[u];
#pragma unroll
    for (int i = 0; i < 8; ++i) {
      int l = t + i * 256;
      int r = l >> 7, c = l & 127;
      Ys[r][c] = Yb[(size_t)(kk + r) * E_ + c];
    }
    __syncthreads();
#pragma unroll
    for (int k = 0; k < 16; ++k) {
      float av[8], yv[8];
#pragma unroll
      for (int i = 0; i < 8; ++i) av[i] = As[k][tx + 16 * i];
#pragma unroll
      for (int j = 0; j < 8; ++j) yv[j] = Ys[k][ty + 16 * j];
#pragma unroll
      for (int i = 0; i < 8; ++i)
#pragma unroll
        for (int j = 0; j < 8; ++j) acc[i][j] = fmaf(av[i], yv[j], acc[i][j]);
    }
    __syncthreads();
  }
#pragma unroll
  for (int i = 0; i < 8; ++i)
#pragma unroll
    for (int j = 0; j < 8; ++j)
      outb[(size_t)(tx + 16 * i) * E_ + ty + 16 * j] = acc[i][j];
}

// ---------------------------------------------------------------------------
// Linear: out[row,o] = sum_k In[row,k]*W[o,k] + bias[o]; M=32768,K=128,N=128
// ---------------------------------------------------------------------------
__global__ __launch_bounds__(256) void k_lin(const float* __restrict__ In,
                                             const float* __restrict__ W,
                                             const float* __restrict__ bias,
                                             float* __restrict__ out) {
  size_t row0 = (size_t)blockIdx.x * 128;
  __shared__ float Is[16][129];
  __shared__ float Ws[16][129];
  int t = threadIdx.x;
  int tx = t & 15, ty = t >> 4;
  int rrow = t >> 1, part = t & 1;
  float acc[8][8] = {};

  for (int kk = 0; kk < 128; kk += 16) {
    const float* si = &In[(row0 + rrow) * 128 + kk + part * 8];
    const float* sw = &W[(size_t)rrow * 128 + kk + part * 8];
#pragma unroll
    for (int u = 0; u < 8; ++u) {
      Is[part * 8 + u][rrow] = si[u];
      Ws[part * 8 + u][rrow] = sw[u];
    }
    __syncthreads();
#pragma unroll
    for (int k = 0; k < 16; ++k) {
      float av[8], wv[8];
#pragma unroll
      for (int i = 0; i < 8; ++i) av[i] = Is[k][tx + 16 * i];
#pragma unroll
      for (int j = 0; j < 8; ++j) wv[j] = Ws[k][ty + 16 * j];
#pragma unroll
      for (int i = 0; i < 8; ++i)
#pragma unroll
        for (int j = 0; j < 8; ++j) acc[i][j] = fmaf(av[i], wv[j], acc[i][j]);
    }
    __syncthreads();
  }
#pragma unroll
  for (int i = 0; i < 8; ++i)
#pragma unroll
    for (int j = 0; j < 8; ++j)
      out[(row0 + tx + 16 * i) * 128 + ty + 16 * j] = acc[i][j] + bias[ty + 16 * j];
}

// ---------------------------------------------------------------------------
// Fused LN + tanh + optional residual-add: out = tanh(LN(in))*g+b (+ add)
// One wave per 128-wide row.
// ---------------------------------------------------------------------------
__global__ __launch_bounds__(256) void k_ln_tanh(const float* __restrict__ in,
                                                 const float* __restrict__ gam,
                                                 const float* __restrict__ bet,
                                                 const float* __restrict__ addp,
                                                 float* __restrict__ out) {
  size_t wid = ((size_t)blockIdx.x * 256 + threadIdx.x) >> 6;
  int lane = threadIdx.x & 63;
  const float* r = in + wid * E_;
  float x0 = r[lane], x1 = r[lane + 64];
  float s = x0 + x1;
  float s2 = x0 * x0 + x1 * x1;
#pragma unroll
  for (int off = 32; off >= 1; off >>= 1) {
    s  += __shfl_xor(s, off);
    s2 += __shfl_xor(s2, off);
  }
  float mu  = s * (1.0f / 128.0f);
  float var = s2 * (1.0f / 128.0f) - mu * mu;
  float rstd = rsqrtf(var + 1e-5f);
  float t0 = tanhf((x0 - mu) * rstd * gam[lane] + bet[lane]);
  float t1 = tanhf((x1 - mu) * rstd * gam[lane + 64] + bet[lane + 64]);
  if (addp) {
    t0 += addp[wid * E_ + lane];
    t1 += addp[wid * E_ + lane + 64];
  }
  out[wid * E_ + lane] = t0;
  out[wid * E_ + lane + 64] = t1;
}

// ---------------------------------------------------------------------------
// Fused KAN layer (o=128): out[row,o] = sum_i act(x)*W9p[i*9+0][o]
//                                     + sum_{i,q} bs_q(x)*W9p[i*9+1+q][o]
// K=1152 streamed as 64 chunks of 18 (2 input channels x 9).
// ACT: 0 = silu
// ---------------------------------------------------------------------------
template <int ACT>
__global__ __launch_bounds__(256) void k_kan(const float* __restrict__ xin,
                                             const float* __restrict__ W9p,
                                             float* __restrict__ out) {
  size_t row0 = (size_t)blockIdx.x * 128;
  __shared__ float As[18][129];
  __shared__ float Ws[18][128];
  int t = threadIdx.x;
  int tx = t & 15, ty = t >> 4;
  int r = t & 127, ii = t >> 7;
  float acc[8][8] = {};

  for (int chunk = 0; chunk < 64; ++chunk) {
    int i0 = chunk * 2;
    float xv = xin[(row0 + r) * E_ + i0 + ii];
    float vals[9];
    if (ACT == 0) {
      vals[0] = xv / (1.0f + expf(-xv));  // silu
    } else {
      vals[0] = 1.0f / (1.0f + expf(-xv));  // sigmoid
    }
    bspline8(xv, &vals[1]);
#pragma unroll
    for (int q = 0; q < 9; ++q) As[ii * 9 + q][r] = vals[q];
#pragma unroll
    for (int i = 0; i < 9; ++i) {
      int l = t + i * 256;
      int rr = l >> 7, c = l & 127;
      Ws[rr][c] = W9p[(size_t)(chunk * 18 + rr) * 128 + c];
    }
    __syncthreads();
#pragma unroll
    for (int k = 0; k < 18; ++k) {
      float av[8], wv[8];
#pragma unroll
      for (int i = 0; i < 8; ++i) av[i] = As[k][tx + 16 * i];
#pragma unroll
      for (int j = 0; j < 8; ++j) wv[j] = Ws[k][ty + 16 * j];
#pragma unroll
      for (int i = 0; i < 8; ++i)
#pragma unroll
        for (int j = 0; j < 8; ++j) acc[i][j] = fmaf(av[i], wv[j], acc[i][j]);
    }
    __syncthreads();
  }
#pragma unroll
  for (int i = 0; i < 8; ++i)
#pragma unroll
    for (int j = 0; j < 8; ++j)
      out[(row0 + tx + 16 * i) * E_ + ty + 16 * j] = acc[i][j];
}

// ---------------------------------------------------------------------------
// KAN3 (o=1) + final affine: out[row] = 0.6*(sum_i sigmoid(x)*w3[i*9]
//                                     + sum_{i,q} bs_q*w3[i*9+1+q]) + 0.2
// One wave per row.
// ---------------------------------------------------------------------------
__global__ __launch_bounds__(256) void k_kan3(const float* __restrict__ xin,
                                              const float* __restrict__ w3,
                                              float* __restrict__ out) {
  size_t wid = ((size_t)blockIdx.x * 256 + threadIdx.x) >> 6;
  int lane = threadIdx.x & 63;
  const float* xr = xin + wid * E_;
  float s = 0.f;
#pragma unroll
  for (int half = 0; half < 2; ++half) {
    int i = lane + half * 64;
    float xv = xr[i];
    float sig = 1.0f / (1.0f + expf(-xv));
    const float* w = w3 + i * 9;
    s = fmaf(sig, w[0], s);
    float bs[8];
    bspline8(xv, bs);
#pragma unroll
    for (int q = 0; q < 8; ++q) s = fmaf(bs[q], w[1 + q], s);
  }
#pragma unroll
  for (int off = 32; off >= 1; off >>= 1) s += __shfl_xor(s, off);
  if (lane == 0) out[wid] = s * 0.6f + 0.2f;
}

// ---------------------------------------------------------------------------
extern "C" void kernel_launch(void* const* d_in, const int* in_sizes, int n_in,
                              void* d_out, int out_size, void* d_ws, size_t ws_size,
                              hipStream_t stream) {
  (void)in_sizes; (void)n_in; (void)out_size; (void)ws_size;
  const float* obs   = (const float*)d_in[0];
  const float* W_emb = (const float*)d_in[1];
  const float* ln1_g = (const float*)d_in[2];
  const float* ln1_b = (const float*)d_in[3];
  const float* ln2_g = (const float*)d_in[4];
  const float* ln2_b = (const float*)d_in[5];
  const float* ln3_g = (const float*)d_in[6];
  const float* ln3_b = (const float*)d_in[7];
  const float* ln4_g = (const float*)d_in[8];
  const float* ln4_b = (const float*)d_in[9];
  const float* lin1_w = (const float*)d_in[10];
  const float* lin1_b = (const float*)d_in[11];
  const float* lin2_w = (const float*)d_in[12];
  const float* lin2_b = (const float*)d_in[13];
  const float* lin3_w = (const float*)d_in[14];
  const float* lin3_b = (const float*)d_in[15];
  const float* kan1_base = (const float*)d_in[16];
  const float* kan1_spline = (const float*)d_in[17];
  const float* kan1_scaler = (const float*)d_in[18];
  const float* kan2_base = (const float*)d_in[19];
  const float* kan2_spline = (const float*)d_in[20];
  const float* kan2_scaler = (const float*)d_in[21];
  const float* kan3_base = (const float*)d_in[22];
  const float* kan3_spline = (const float*)d_in[23];
  const float* kan3_scaler = (const float*)d_in[24];

  float* ws = (float*)d_ws;
  const size_t T = (size_t)ROWS_ * E_;  // 4,194,304 floats
  float* X    = ws;
  float* XCC  = ws + T;
  float* XCV  = ws + 2 * T;
  float* T1   = ws + 3 * T;
  float* T2   = ws + 4 * T;
  float* W9p1 = ws + 5 * T;
  float* W9p2 = W9p1 + 1152 * 128;
  float* w3v  = W9p2 + 1152 * 128;

  // Pack KAN weights
  k_pack9<<<576, 256, 0, stream>>>(kan1_base, kan1_spline, kan1_scaler, W9p1, 128);
  k_pack9<<<576, 256, 0, stream>>>(kan2_base, kan2_spline, kan2_scaler, W9p2, 128);
  k_pack9<<<5, 256, 0, stream>>>(kan3_base, kan3_spline, kan3_scaler, w3v, 1);

  // 1. X = embed(obs)
  k_embed<<<ROWS_ / 2, 256, 0, stream>>>(obs, W_emb, X);
  // 2. T1 = A^T X  (bce)
  k_einsum_at<<<256, 256, 0, stream>>>(obs, X, T1);
  // 3. XCC = tanh(LN1(T1))
  k_ln_tanh<<<ROWS_ / 4, 256, 0, stream>>>(T1, ln1_g, ln1_b, nullptr, XCC);
  // 4. T2 = XCC @ W1^T + b1
  k_lin<<<256, 256, 0, stream>>>(XCC, lin1_w, lin1_b, T2);
  // 5. T1 = A T2  (bve)
  k_einsum_a<<<256, 256, 0, stream>>>(obs, T2, T1);
  // 6. XCV = tanh(LN2(T1)) + X
  k_ln_tanh<<<ROWS_ / 4, 256, 0, stream>>>(T1, ln2_g, ln2_b, X, XCV);
  // 7. T2 = XCV @ W2^T + b2
  k_lin<<<256, 256, 0, stream>>>(XCV, lin2_w, lin2_b, T2);
  // 8. T1 = A^T T2  (bce)
  k_einsum_at<<<256, 256, 0, stream>>>(obs, T2, T1);
  // 9. T2 = tanh(LN3(T1)) + XCC
  k_ln_tanh<<<ROWS_ / 4, 256, 0, stream>>>(T1, ln3_g, ln3_b, XCC, T2);
  // 10. T1 = T2 @ W3^T + b3
  k_lin<<<256, 256, 0, stream>>>(T2, lin3_w, lin3_b, T1);
  // 11. T2 = A T1  (bve)
  k_einsum_a<<<256, 256, 0, stream>>>(obs, T1, T2);
  // 12. X = tanh(LN4(T2)) + XCV   (final features, reuse X)
  k_ln_tanh<<<ROWS_ / 4, 256, 0, stream>>>(T2, ln4_g, ln4_b, XCV, X);
  // 13. T1 = KAN1(X)  (silu)
  k_kan<0><<<256, 256, 0, stream>>>(X, W9p1, T1);
  // 14. T2 = KAN2(T1) (silu)
  k_kan<0><<<256, 256, 0, stream>>>(T1, W9p2, T2);
  // 15. out = KAN3(T2) * 0.6 + 0.2  (sigmoid act)
  k_kan3<<<ROWS_ / 4, 256, 0, stream>>>(T2, w3v, (float*)d_out);
}

// Round 8
// 626.301 us; speedup vs baseline: 2.3113x; 2.3113x over previous
//
#include <hip/hip_runtime.h>
#include <math.h>

typedef __attribute__((ext_vector_type(8))) _Float16 h8;   // 8 f16 (4 VGPR) MFMA A/B frag
typedef __attribute__((ext_vector_type(4))) _Float16 h4v;  // 4 f16 (8B)
typedef __attribute__((ext_vector_type(4))) float f4;      // MFMA C/D frag

static constexpr int B_   = 32;
static constexpr int NV_  = 1024;
static constexpr int NC_  = 1024;
static constexpr int COL_ = 1038;
static constexpr int NF_  = 14;
static constexpr int E_   = 128;
static constexpr int ROWS_ = B_ * NV_;   // 32768

__device__ __forceinline__ _Float16 f2h(float f) { return (_Float16)f; }

// ---------------------------------------------------------------------------
// Cubic B-spline closed form. Grid g[j] = (j-3)*0.4 - 1. For cell
// c = floor((x+2.2)/0.4), basis j (0..7) = piece (c-j) of cardinal B3 at
// local t. Out-of-range c gives all-zero automatically (no p in 0..3).
// ---------------------------------------------------------------------------
__device__ __forceinline__ void bsp(float x, float& P0, float& P1, float& P2,
                                    float& P3, int& c) {
  float u = fmaf(x, 2.5f, 5.5f);
  float cf = floorf(u);
  c = (int)cf;
  float t = u - cf;
  float t2 = t * t, t3 = t2 * t;
  float omt = 1.f - t;
  P0 = t3 * (1.f / 6.f);                                        // j == c
  P1 = fmaf(-3.f, t3, fmaf(3.f, t2, fmaf(3.f, t, 1.f))) * (1.f / 6.f);
  P2 = fmaf(3.f, t3, fmaf(-6.f, t2, 4.f)) * (1.f / 6.f);
  P3 = omt * omt * omt * (1.f / 6.f);                           // j == c-3
}
__device__ __forceinline__ float bsel(int p, float P0, float P1, float P2, float P3) {
  float v = 0.f;
  v = (p == 0) ? P0 : v; v = (p == 1) ? P1 : v;
  v = (p == 2) ? P2 : v; v = (p == 3) ? P3 : v;
  return v;
}

// ---------------------------------------------------------------------------
// Small prep kernels
// ---------------------------------------------------------------------------
__global__ void k_f32f16(const float* __restrict__ src, _Float16* __restrict__ dst, int n) {
  int idx = blockIdx.x * 256 + threadIdx.x;
  if (idx < n) dst[idx] = f2h(src[idx]);
}

// KAN weights -> [o=128][k=2048] f16, k = ch*16 + q (q=0 act, 1..8 spline, rest 0)
__global__ void k_pack16(const float* __restrict__ base, const float* __restrict__ spline,
                         const float* __restrict__ scaler, _Float16* __restrict__ W9t) {
  int idx = blockIdx.x * 256 + threadIdx.x;   // < 262144
  int o = idx >> 11, k = idx & 2047, ch = k >> 4, q = k & 15;
  float v = 0.f;
  if (q == 0) v = base[o * 128 + ch];
  else if (q <= 8) v = spline[(o * 128 + ch) * 8 + q - 1] * scaler[o * 128 + ch];
  W9t[idx] = f2h(v);
}

// kan3 (O=1) fp32 pack: w3[i*9+q]
__global__ void k_pack9k3(const float* __restrict__ base, const float* __restrict__ spline,
                          const float* __restrict__ scaler, float* __restrict__ w3) {
  int idx = blockIdx.x * 256 + threadIdx.x;
  if (idx >= 1152) return;
  int i = idx / 9, q = idx % 9;
  w3[idx] = (q == 0) ? base[i] : spline[i * 8 + q - 1] * scaler[i];
}

// ---------------------------------------------------------------------------
// Embedding: X[row,e] = sum_f obs[row*COL_+f] * W_emb[e*14+f]
// ---------------------------------------------------------------------------
__global__ __launch_bounds__(256) void k_embed(const float* __restrict__ obs,
                                               const float* __restrict__ W_emb,
                                               float* __restrict__ X) {
  int t = threadIdx.x;
  int e = t & 127;
  size_t row = (size_t)blockIdx.x * 2 + (t >> 7);
  float w[NF_];
#pragma unroll
  for (int f = 0; f < NF_; ++f) w[f] = W_emb[e * NF_ + f];
  const float* orow = obs + row * COL_;
  float acc = 0.f;
#pragma unroll
  for (int f = 0; f < NF_; ++f) acc = fmaf(orow[f], w[f], acc);
  X[row * E_ + e] = acc;
}

// ---------------------------------------------------------------------------
// Transpose-convert X fp32 [b][v][128] -> f16 [b][e][1024] via LDS tiles.
// ---------------------------------------------------------------------------
__global__ __launch_bounds__(256) void k_transX(const float* __restrict__ Xf,
                                                _Float16* __restrict__ Xt) {
  int vt = blockIdx.x, et = blockIdx.y, b = blockIdx.z;
  __shared__ float tile[64][65];
  int t = threadIdx.x;
  int el = t & 63, q = t >> 6;
  const float* src = Xf + (size_t)b * 131072;
#pragma unroll 4
  for (int r = 0; r < 16; ++r) {
    int vl = q * 16 + r;
    tile[vl][el] = src[(size_t)(vt * 64 + vl) * 128 + et * 64 + el];
  }
  __syncthreads();
  _Float16* dst = Xt + (size_t)b * 131072;
#pragma unroll 4
  for (int r = 0; r < 16; ++r) {
    int el2 = q * 16 + r;
    dst[(size_t)(et * 64 + el2) * 1024 + vt * 64 + el] = f2h(tile[el][el2]);
  }
}

// ---------------------------------------------------------------------------
// einsum 'bvc,bve->bce' (MFMA): out[b,c,e] = sum_v A[b,v,c] * X[b,v,e]
// A-frags: strided fp32 loads from obs + cvt. B-frags: f16 [b][e][v] direct.
// grid 256 = 32b x 8 c-tiles; 4 waves 2x2, each 64x64.
// ---------------------------------------------------------------------------
__global__ __launch_bounds__(256) void k_einsum_at(const float* __restrict__ obs,
                                                   const _Float16* __restrict__ Bt,
                                                   float* __restrict__ out) {
  int blk = blockIdx.x;
  int b = blk >> 3, ct = blk & 7;
  const float* obsb = obs + (size_t)b * NV_ * COL_;
  const _Float16* Btb = Bt + (size_t)b * 131072;
  float* outb = out + (size_t)b * 131072;
  int t = threadIdx.x, w = t >> 6, l = t & 63;
  int l15 = l & 15, g = l >> 4;
  int wR = (w >> 1) * 64, wC = (w & 1) * 64;
  int c0 = ct * 128;
  f4 acc[4][4] = {};

#pragma unroll 2
  for (int kk = 0; kk < NV_; kk += 32) {
    h8 af[4], bf[4];
#pragma unroll
    for (int m = 0; m < 4; ++m) {
      int c = c0 + wR + m * 16 + l15;
      const float* ap = obsb + (size_t)(kk + g * 8) * COL_ + NF_ + c;
#pragma unroll
      for (int j = 0; j < 8; ++j) af[m][j] = f2h(ap[(size_t)j * COL_]);
    }
#pragma unroll
    for (int n = 0; n < 4; ++n) {
      int e = wC + n * 16 + l15;
      bf[n] = *(const h8*)(Btb + (size_t)e * 1024 + kk + g * 8);
    }
#pragma unroll
    for (int m = 0; m < 4; ++m)
#pragma unroll
      for (int n = 0; n < 4; ++n)
        acc[m][n] = __builtin_amdgcn_mfma_f32_16x16x32_f16(af[m], bf[n], acc[m][n], 0, 0, 0);
  }
#pragma unroll
  for (int m = 0; m < 4; ++m)
#pragma unroll
    for (int n = 0; n < 4; ++n)
#pragma unroll
      for (int rr = 0; rr < 4; ++rr)
        outb[(size_t)(c0 + wR + m * 16 + g * 4 + rr) * 128 + wC + n * 16 + l15] = acc[m][n][rr];
}

// ---------------------------------------------------------------------------
// einsum 'bvc,bce->bve' (MFMA): out[b,v,e] = sum_c A[b,v,c] * Y[b,c,e]
// A-frags: contiguous fp32 (float2 x4) from obs + cvt. B-frags: f16 [b][e][c].
// ---------------------------------------------------------------------------
__global__ __launch_bounds__(256) void k_einsum_a(const float* __restrict__ obs,
                                                  const _Float16* __restrict__ Bt,
                                                  float* __restrict__ out) {
  int blk = blockIdx.x;
  int b = blk >> 3, vt = blk & 7;
  const float* obsb = obs + (size_t)b * NV_ * COL_;
  const _Float16* Btb = Bt + (size_t)b * 131072;
  float* outb = out + (size_t)b * 131072;
  int t = threadIdx.x, w = t >> 6, l = t & 63;
  int l15 = l & 15, g = l >> 4;
  int wR = (w >> 1) * 64, wC = (w & 1) * 64;
  int v0 = vt * 128;
  f4 acc[4][4] = {};

#pragma unroll 2
  for (int kk = 0; kk < NC_; kk += 32) {
    h8 af[4], bf[4];
#pragma unroll
    for (int m = 0; m < 4; ++m) {
      int v = v0 + wR + m * 16 + l15;
      const float2* ap = (const float2*)(obsb + (size_t)v * COL_ + NF_ + kk + g * 8);
      float2 p0 = ap[0], p1 = ap[1], p2 = ap[2], p3 = ap[3];
      af[m][0] = f2h(p0.x); af[m][1] = f2h(p0.y);
      af[m][2] = f2h(p1.x); af[m][3] = f2h(p1.y);
      af[m][4] = f2h(p2.x); af[m][5] = f2h(p2.y);
      af[m][6] = f2h(p3.x); af[m][7] = f2h(p3.y);
    }
#pragma unroll
    for (int n = 0; n < 4; ++n) {
      int e = wC + n * 16 + l15;
      bf[n] = *(const h8*)(Btb + (size_t)e * 1024 + kk + g * 8);
    }
#pragma unroll
    for (int m = 0; m < 4; ++m)
#pragma unroll
      for (int n = 0; n < 4; ++n)
        acc[m][n] = __builtin_amdgcn_mfma_f32_16x16x32_f16(af[m], bf[n], acc[m][n], 0, 0, 0);
  }
#pragma unroll
  for (int m = 0; m < 4; ++m)
#pragma unroll
    for (int n = 0; n < 4; ++n)
#pragma unroll
      for (int rr = 0; rr < 4; ++rr)
        outb[(size_t)(v0 + wR + m * 16 + g * 4 + rr) * 128 + wC + n * 16 + l15] = acc[m][n][rr];
}

// ---------------------------------------------------------------------------
// Linear (MFMA): out[row,o] = In[row,:]@W[o,:] + bias[o]; writes output
// TRANSPOSED f16 per-batch: outT[b][o][row_in_batch].
// ---------------------------------------------------------------------------
__global__ __launch_bounds__(256) void k_lin(const _Float16* __restrict__ Inb,
                                             const _Float16* __restrict__ Wb,
                                             const float* __restrict__ bias,
                                             _Float16* __restrict__ outT) {
  int row0 = blockIdx.x * 128;
  int b = row0 >> 10, vb = row0 & 1023;
  int t = threadIdx.x, w = t >> 6, l = t & 63;
  int l15 = l & 15, g = l >> 4;
  int wR = (w >> 1) * 64, wC = (w & 1) * 64;
  f4 acc[4][4] = {};

#pragma unroll
  for (int kk = 0; kk < 128; kk += 32) {
    h8 af[4], bf[4];
#pragma unroll
    for (int m = 0; m < 4; ++m)
      af[m] = *(const h8*)(Inb + (size_t)(row0 + wR + m * 16 + l15) * 128 + kk + g * 8);
#pragma unroll
    for (int n = 0; n < 4; ++n)
      bf[n] = *(const h8*)(Wb + (size_t)(wC + n * 16 + l15) * 128 + kk + g * 8);
#pragma unroll
    for (int m = 0; m < 4; ++m)
#pragma unroll
      for (int n = 0; n < 4; ++n)
        acc[m][n] = __builtin_amdgcn_mfma_f32_16x16x32_f16(af[m], bf[n], acc[m][n], 0, 0, 0);
  }
#pragma unroll
  for (int m = 0; m < 4; ++m)
#pragma unroll
    for (int n = 0; n < 4; ++n) {
      int col = wC + n * 16 + l15;
      float bv = bias[col];
      h4v sv;
#pragma unroll
      for (int rr = 0; rr < 4; ++rr) sv[rr] = f2h(acc[m][n][rr] + bv);
      *(h4v*)(outT + (size_t)b * 131072 + (size_t)col * 1024 + vb + wR + m * 16 + g * 4) = sv;
    }
}

// ---------------------------------------------------------------------------
// Fused LN + tanh + optional residual; writes fp32 AND f16.
// (no __restrict__: outf may alias addp — per-element read-then-write is safe)
// ---------------------------------------------------------------------------
__global__ __launch_bounds__(256) void k_ln(const float* in, const float* gam,
                                            const float* bet, const float* addp,
                                            float* outf, _Float16* outb) {
  size_t wid = ((size_t)blockIdx.x * 256 + threadIdx.x) >> 6;
  int lane = threadIdx.x & 63;
  const float* r = in + wid * E_;
  float x0 = r[lane], x1 = r[lane + 64];
  float s = x0 + x1;
  float s2 = x0 * x0 + x1 * x1;
#pragma unroll
  for (int off = 32; off >= 1; off >>= 1) {
    s += __shfl_xor(s, off);
    s2 += __shfl_xor(s2, off);
  }
  float mu = s * (1.0f / 128.0f);
  float var = s2 * (1.0f / 128.0f) - mu * mu;
  float rstd = rsqrtf(var + 1e-5f);
  float t0 = tanhf((x0 - mu) * rstd * gam[lane] + bet[lane]);
  float t1 = tanhf((x1 - mu) * rstd * gam[lane + 64] + bet[lane + 64]);
  if (addp) {
    t0 += addp[wid * E_ + lane];
    t1 += addp[wid * E_ + lane + 64];
  }
  outf[wid * E_ + lane] = t0;
  outf[wid * E_ + lane + 64] = t1;
  outb[wid * E_ + lane] = f2h(t0);
  outb[wid * E_ + lane + 64] = f2h(t1);
}

// ---------------------------------------------------------------------------
// Fused KAN (o=128, MFMA): bases computed closed-form into XOR-swizzled LDS,
// K padded to 16/channel (2048). W9t read global-direct. ACT 0 = silu.
// ---------------------------------------------------------------------------
template <int ACT>
__global__ __launch_bounds__(256) void k_kan(const float* __restrict__ Xin,
                                             const _Float16* __restrict__ W9t,
                                             float* __restrict__ out) {
  int row0 = blockIdx.x * 128;
  __shared__ float xs[128 * 129];
  __shared__ _Float16 As[128 * 64];   // [row][4ch*16] f16, 128B rows, XOR-swizzled
  int t = threadIdx.x, w = t >> 6, l = t & 63;
  int l15 = l & 15, g = l >> 4;
  int wR = (w >> 1) * 64, wC = (w & 1) * 64;
  int rr_ = t & 127, sub = t >> 7;

  // stage x-tile (coalesced), padded stride 129
#pragma unroll
  for (int p = 0; p < 16; ++p) {
    int idx4 = (p * 256 + t) * 4;
    int r = idx4 >> 7, c4 = idx4 & 127;
    const f4 v = *(const f4*)(Xin + (size_t)(row0 + r) * 128 + c4);
    xs[r * 129 + c4] = v[0]; xs[r * 129 + c4 + 1] = v[1];
    xs[r * 129 + c4 + 2] = v[2]; xs[r * 129 + c4 + 3] = v[3];
  }
  __syncthreads();

  f4 acc[4][4] = {};
  for (int chunk = 0; chunk < 32; ++chunk) {
#pragma unroll
    for (int s = 0; s < 2; ++s) {
      int cl = sub * 2 + s;            // 0..3
      int ch = chunk * 4 + cl;
      float x = xs[rr_ * 129 + ch];
      float act;
      if (ACT == 0) act = x / (1.f + __expf(-x));
      else          act = 1.f / (1.f + __expf(-x));
      float P0, P1, P2, P3; int c;
      bsp(x, P0, P1, P2, P3, c);
      h8 lo, hi;
      lo[0] = f2h(act);
#pragma unroll
      for (int j = 0; j < 7; ++j) lo[1 + j] = f2h(bsel(c - j, P0, P1, P2, P3));
      hi[0] = f2h(bsel(c - 7, P0, P1, P2, P3));
#pragma unroll
      for (int q = 1; q < 8; ++q) hi[q] = (_Float16)0.f;
      int sw = (rr_ & 7) << 4;
      *(h8*)((char*)As + rr_ * 128 + ((cl * 32) ^ sw)) = lo;
      *(h8*)((char*)As + rr_ * 128 + ((cl * 32 + 16) ^ sw)) = hi;
    }
    __syncthreads();
#pragma unroll
    for (int ks = 0; ks < 2; ++ks) {
      h8 af[4], bf[4];
#pragma unroll
      for (int m = 0; m < 4; ++m) {
        int r = wR + m * 16 + l15;
        int cb = (ks * 64 + g * 16) ^ ((r & 7) << 4);
        af[m] = *(h8*)((char*)As + r * 128 + cb);
      }
#pragma unroll
      for (int n = 0; n < 4; ++n) {
        int col = wC + n * 16 + l15;
        bf[n] = *(const h8*)(W9t + (size_t)col * 2048 + chunk * 64 + ks * 32 + g * 8);
      }
#pragma unroll
      for (int m = 0; m < 4; ++m)
#pragma unroll
        for (int n = 0; n < 4; ++n)
          acc[m][n] = __builtin_amdgcn_mfma_f32_16x16x32_f16(af[m], bf[n], acc[m][n], 0, 0, 0);
    }
    __syncthreads();
  }
#pragma unroll
  for (int m = 0; m < 4; ++m)
#pragma unroll
    for (int n = 0; n < 4; ++n)
#pragma unroll
      for (int rr = 0; rr < 4; ++rr)
        out[(size_t)(row0 + wR + m * 16 + g * 4 + rr) * 128 + wC + n * 16 + l15] = acc[m][n][rr];
}

// ---------------------------------------------------------------------------
// KAN3 (o=1, fp32) + final affine. One wave per row.
// ---------------------------------------------------------------------------
__global__ __launch_bounds__(256) void k_kan3(const float* __restrict__ xin,
                                              const float* __restrict__ w3,
                                              float* __restrict__ out) {
  size_t wid = ((size_t)blockIdx.x * 256 + threadIdx.x) >> 6;
  int lane = threadIdx.x & 63;
  const float* xr = xin + wid * E_;
  float s = 0.f;
#pragma unroll
  for (int half = 0; half < 2; ++half) {
    int i = lane + half * 64;
    float x = xr[i];
    float sig = 1.f / (1.f + __expf(-x));
    const float* ww = w3 + i * 9;
    s = fmaf(sig, ww[0], s);
    float P0, P1, P2, P3; int c;
    bsp(x, P0, P1, P2, P3, c);
#pragma unroll
    for (int j = 0; j < 8; ++j) s = fmaf(bsel(c - j, P0, P1, P2, P3), ww[1 + j], s);
  }
#pragma unroll
  for (int off = 32; off >= 1; off >>= 1) s += __shfl_xor(s, off);
  if (lane == 0) out[wid] = s * 0.6f + 0.2f;
}

// ---------------------------------------------------------------------------
extern "C" void kernel_launch(void* const* d_in, const int* in_sizes, int n_in,
                              void* d_out, int out_size, void* d_ws, size_t ws_size,
                              hipStream_t stream) {
  (void)in_sizes; (void)n_in; (void)out_size; (void)ws_size;
  const float* obs   = (const float*)d_in[0];
  const float* W_emb = (const float*)d_in[1];
  const float* ln1_g = (const float*)d_in[2];
  const float* ln1_b = (const float*)d_in[3];
  const float* ln2_g = (const float*)d_in[4];
  const float* ln2_b = (const float*)d_in[5];
  const float* ln3_g = (const float*)d_in[6];
  const float* ln3_b = (const float*)d_in[7];
  const float* ln4_g = (const float*)d_in[8];
  const float* ln4_b = (const float*)d_in[9];
  const float* lin1_w = (const float*)d_in[10];
  const float* lin1_b = (const float*)d_in[11];
  const float* lin2_w = (const float*)d_in[12];
  const float* lin2_b = (const float*)d_in[13];
  const float* lin3_w = (const float*)d_in[14];
  const float* lin3_b = (const float*)d_in[15];
  const float* kan1_base = (const float*)d_in[16];
  const float* kan1_spline = (const float*)d_in[17];
  const float* kan1_scaler = (const float*)d_in[18];
  const float* kan2_base = (const float*)d_in[19];
  const float* kan2_spline = (const float*)d_in[20];
  const float* kan2_scaler = (const float*)d_in[21];
  const float* kan3_base = (const float*)d_in[22];
  const float* kan3_spline = (const float*)d_in[23];
  const float* kan3_scaler = (const float*)d_in[24];

  char* wsb = (char*)d_ws;
  const size_t MB16 = (size_t)1 << 24;
  const size_t MB8  = (size_t)1 << 23;
  float* Xf  = (float*)(wsb);
  float* XCC = (float*)(wsb + MB16);
  float* XCV = (float*)(wsb + 2 * MB16);
  float* T1  = (float*)(wsb + 3 * MB16);
  _Float16* LTt = (_Float16*)(wsb + 4 * MB16);          // 8MB, also reused as Xt
  _Float16* LNb = (_Float16*)(wsb + 4 * MB16 + MB8);    // 8MB
  char*  p   = wsb + 4 * MB16 + 2 * MB8;
  _Float16* W9t1 = (_Float16*)p;      p += 128 * 2048 * 2;
  _Float16* W9t2 = (_Float16*)p;      p += 128 * 2048 * 2;
  _Float16* Wb1  = (_Float16*)p;      p += 128 * 128 * 2;
  _Float16* Wb2  = (_Float16*)p;      p += 128 * 128 * 2;
  _Float16* Wb3  = (_Float16*)p;      p += 128 * 128 * 2;
  float* w3v  = (float*)p;

  // weight prep
  k_f32f16<<<64, 256, 0, stream>>>(lin1_w, Wb1, 16384);
  k_f32f16<<<64, 256, 0, stream>>>(lin2_w, Wb2, 16384);
  k_f32f16<<<64, 256, 0, stream>>>(lin3_w, Wb3, 16384);
  k_pack16<<<1024, 256, 0, stream>>>(kan1_base, kan1_spline, kan1_scaler, W9t1);
  k_pack16<<<1024, 256, 0, stream>>>(kan2_base, kan2_spline, kan2_scaler, W9t2);
  k_pack9k3<<<5, 256, 0, stream>>>(kan3_base, kan3_spline, kan3_scaler, w3v);

  // 1. X = embed(obs); Xt = transpose(X) f16
  k_embed<<<ROWS_ / 2, 256, 0, stream>>>(obs, W_emb, Xf);
  k_transX<<<dim3(16, 2, 32), 256, 0, stream>>>(Xf, LTt);
  // 2. T1 = A^T X
  k_einsum_at<<<256, 256, 0, stream>>>(obs, LTt, T1);
  // 3. XCC = tanh(LN1(T1))
  k_ln<<<ROWS_ / 4, 256, 0, stream>>>(T1, ln1_g, ln1_b, nullptr, XCC, LNb);
  // 4. LTt = (XCC @ W1^T + b1)^T f16
  k_lin<<<256, 256, 0, stream>>>(LNb, Wb1, lin1_b, LTt);
  // 5. T1 = A @ lin1out
  k_einsum_a<<<256, 256, 0, stream>>>(obs, LTt, T1);
  // 6. XCV = tanh(LN2(T1)) + X
  k_ln<<<ROWS_ / 4, 256, 0, stream>>>(T1, ln2_g, ln2_b, Xf, XCV, LNb);
  // 7. lin2
  k_lin<<<256, 256, 0, stream>>>(LNb, Wb2, lin2_b, LTt);
  // 8. T1 = A^T lin2out
  k_einsum_at<<<256, 256, 0, stream>>>(obs, LTt, T1);
  // 9. tanh(LN3(T1)) + XCC  (f32 clobbers XCC; f16 -> LNb for lin3)
  k_ln<<<ROWS_ / 4, 256, 0, stream>>>(T1, ln3_g, ln3_b, XCC, XCC, LNb);
  // 10. lin3
  k_lin<<<256, 256, 0, stream>>>(LNb, Wb3, lin3_b, LTt);
  // 11. T1 = A @ lin3out
  k_einsum_a<<<256, 256, 0, stream>>>(obs, LTt, T1);
  // 12. XCC := tanh(LN4(T1)) + XCV   (KAN input)
  k_ln<<<ROWS_ / 4, 256, 0, stream>>>(T1, ln4_g, ln4_b, XCV, XCC, LNb);
  // 13-15. KAN stack
  k_kan<0><<<256, 256, 0, stream>>>(XCC, W9t1, T1);
  k_kan<0><<<256, 256, 0, stream>>>(T1, W9t2, XCV);
  k_kan3<<<ROWS_ / 4, 256, 0, stream>>>(XCV, w3v, (float*)d_out);
}